// Round 5
// baseline (413.988 us; speedup 1.0000x reference)
//
#include <hip/hip_runtime.h>

typedef unsigned short u16;
typedef __attribute__((ext_vector_type(8))) short short8;
typedef __attribute__((ext_vector_type(16))) float f32x16;

#define DIM 2048
#define NROWS 8192
#define SLOPE 0.001f
#define LN_EPS 1e-5f

#define LN_BLOCKS 4096              // 16384 rows, 4 rows (waves) per block
#define WT_BLOCKS 2048              // 2 towers * (2048/64)^2 tiles

__device__ __forceinline__ u16 f2bf(float f) {
    unsigned int u = __float_as_uint(f);
    u += 0x7FFFu + ((u >> 16) & 1u);   // round-to-nearest-even
    return (u16)(u >> 16);
}

__device__ __forceinline__ void gload_lds16(const void* g, void* l) {
    __builtin_amdgcn_global_load_lds(
        (const __attribute__((address_space(1))) void*)g,
        (__attribute__((address_space(3))) void*)l, 16, 0, 0);
}

// ---------------- Kernel 1: fused prep ----------------
// blocks [0, LN_BLOCKS): LayerNorm + bf16 cast, one wave per row.
// blocks [LN_BLOCKS, LN_BLOCKS+WT_BLOCKS): W[k][n] -> Wt[n][k] bf16, 64x64 tile.
__global__ __launch_bounds__(256) void prep_kernel(
    const float* __restrict__ u, const float* __restrict__ v,
    const float* __restrict__ lnu_w, const float* __restrict__ lnu_b,
    const float* __restrict__ lnv_w, const float* __restrict__ lnv_b,
    const float* __restrict__ Wu, const float* __restrict__ Wv,
    u16* __restrict__ Au, u16* __restrict__ Av,
    u16* __restrict__ WtU, u16* __restrict__ WtV)
{
    __shared__ u16 tile[64][66];   // WT staging; stride 66 u16 -> 2-way banks (free)

    if (blockIdx.x < LN_BLOCKS) {
        // ---- LayerNorm path: one wave per row, pure shfl reduce ----
        const int wave = threadIdx.x >> 6;
        const int lane = threadIdx.x & 63;
        const int r = blockIdx.x * 4 + wave;          // 0 .. 2*NROWS-1
        const bool isv = r >= NROWS;
        const int row = isv ? (r - NROWS) : r;
        const float* __restrict__ src = (isv ? v : u) + (size_t)row * DIM;
        const float* __restrict__ gw = isv ? lnv_w : lnu_w;
        const float* __restrict__ gb = isv ? lnv_b : lnu_b;
        u16* __restrict__ dst = (isv ? Av : Au) + (size_t)row * DIM;

        float4 x[8];
        #pragma unroll
        for (int i = 0; i < 8; ++i)
            x[i] = *(const float4*)(src + i * 256 + lane * 4);

        float s = 0.f, s2 = 0.f;
        #pragma unroll
        for (int i = 0; i < 8; ++i) {
            s  += (x[i].x + x[i].y) + (x[i].z + x[i].w);
            s2 += x[i].x*x[i].x + x[i].y*x[i].y + x[i].z*x[i].z + x[i].w*x[i].w;
        }
        #pragma unroll
        for (int m = 1; m < 64; m <<= 1) {
            s  += __shfl_xor(s, m);
            s2 += __shfl_xor(s2, m);
        }
        const float mu = s * (1.0f / DIM);
        const float rstd = rsqrtf(s2 * (1.0f / DIM) - mu * mu + LN_EPS);

        #pragma unroll
        for (int i = 0; i < 8; ++i) {
            const float4 w4 = *(const float4*)(gw + i * 256 + lane * 4);
            const float4 b4 = *(const float4*)(gb + i * 256 + lane * 4);
            union { u16 us[4]; uint2 v2; } pk;
            pk.us[0] = f2bf((x[i].x - mu) * rstd * w4.x + b4.x);
            pk.us[1] = f2bf((x[i].y - mu) * rstd * w4.y + b4.y);
            pk.us[2] = f2bf((x[i].z - mu) * rstd * w4.z + b4.z);
            pk.us[3] = f2bf((x[i].w - mu) * rstd * w4.w + b4.w);
            *(uint2*)(dst + i * 256 + lane * 4) = pk.v2;
        }
    } else {
        // ---- transpose+cast path: 64x64 tile ----
        const int b = blockIdx.x - LN_BLOCKS;          // 0..2047
        const int tower = b >> 10;                     // 1024 tiles per tower
        const int t6 = b & 1023;
        const int n0 = (t6 & 31) * 64;
        const int k0 = (t6 >> 5) * 64;
        const float* __restrict__ src = tower ? Wv : Wu;
        u16* __restrict__ dst = tower ? WtV : WtU;
        const int c  = threadIdx.x & 15;               // col group (4 floats)
        const int rq = threadIdx.x >> 4;               // 0..15

        #pragma unroll
        for (int i = 0; i < 4; ++i) {
            const int k = rq + 16 * i;
            const float4 w = *(const float4*)(src + (size_t)(k0 + k) * DIM + n0 + c * 4);
            union { u16 us[4]; uint2 v2; } pk;
            pk.us[0] = f2bf(w.x); pk.us[1] = f2bf(w.y);
            pk.us[2] = f2bf(w.z); pk.us[3] = f2bf(w.w);
            *(uint2*)&tile[k][c * 4] = pk.v2;
        }
        __syncthreads();
        #pragma unroll
        for (int i = 0; i < 4; ++i) {
            const int n = rq + 16 * i;
            union { u16 us[4]; uint2 v2; } pk;
            #pragma unroll
            for (int j = 0; j < 4; ++j) pk.us[j] = tile[c * 4 + j][n];
            *(uint2*)(dst + (size_t)(n0 + n) * DIM + k0 + c * 4) = pk.v2;
        }
    }
}

// ---------------- Kernel 2: fused dual GEMM + bias + LeakyReLU + row dot ----------------
// 128x128 C tile per block, 256 threads = 4 waves, each wave a 64x64 quadrant
// as a 2x2 grid of 32x32x16 bf16 MFMA. BK=64, global_load_lds width-16 staging.
// LDS swizzle: slot s of row r holds global colblock s ^ (r&7) ^ ((r>>3)&7).
// The extra (r>>3) term gives lanes {l, l+8, l+16, l+24} distinct bank groups
// (the R4 pattern lacked it -> 2^24 conflicts; R3's quad-term had it -> 0).
// C/D layout (m74/m101): col = lane&31, row = (reg&3) + 8*(reg>>2) + 4*(lane>>5).
__global__ __launch_bounds__(256, 3) void fused_gemm_dot(
    const u16* __restrict__ Au, const u16* __restrict__ Av,
    const u16* __restrict__ WtU, const u16* __restrict__ WtV,
    const float* __restrict__ b_u, const float* __restrict__ b_v,
    float* __restrict__ out)
{
    __shared__ u16 smA[128 * 64];
    __shared__ u16 smB[128 * 64];

    const int tid  = threadIdx.x;
    const int wave = tid >> 6;
    const int lane = tid & 63;
    const int l31  = lane & 31;   // fragment row (A) / col (B,C)
    const int khalf = lane >> 5;  // which 8-wide k-half the lane holds
    const int wr = wave >> 1;     // wave row half (0..1)
    const int wc = wave & 1;      // wave col half (0..1)

    const int bm = blockIdx.x;    // 0..63
    const int bn = blockIdx.y;    // 0..15
    const size_t arow0 = (size_t)bm * 128;
    const size_t ncol0 = (size_t)bn * 128;

    // staging: lane covers row (rg + lane>>3); to realize the slot mapping,
    // lane fetches global colblock (lane&7) ^ ((lane>>3)&7) ^ ((rg>>3)&7).
    const int srow = lane >> 3;
    const int sblk0 = (lane & 7) ^ (srow & 7);   // ^ per-instr (rg>>3)&7 below

    // fragment-read row-hash terms (row = wX*64 + i*32 + l31):
    const int rhashA[2] = { ((0 * 4) + (l31 >> 3)) & 7, ((1 * 4) + (l31 >> 3)) & 7 };
    const int l7 = l31 & 7;

    f32x16 acc[2][2];
    unsigned int hu_pk[2][2][8];  // tower-u activations, packed bf16 pairs

    #pragma unroll
    for (int tower = 0; tower < 2; ++tower) {
        const u16* __restrict__ Abase = (tower ? Av : Au) + arow0 * DIM;
        const u16* __restrict__ Bbase = (tower ? WtV : WtU) + ncol0 * DIM;

        #pragma unroll
        for (int mi = 0; mi < 2; ++mi)
            #pragma unroll
            for (int ni = 0; ni < 2; ++ni)
                #pragma unroll
                for (int r = 0; r < 16; ++r)
                    acc[mi][ni][r] = 0.f;

        for (int k0 = 0; k0 < DIM; k0 += 64) {
            #pragma unroll
            for (int i = 0; i < 4; ++i) {
                const int rg = i * 32 + wave * 8;            // wave-uniform row group
                const int scol = (sblk0 ^ ((rg >> 3) & 7)) * 8;
                gload_lds16(Abase + (size_t)(rg + srow) * DIM + k0 + scol, smA + rg * 64);
                gload_lds16(Bbase + (size_t)(rg + srow) * DIM + k0 + scol, smB + rg * 64);
            }
            __syncthreads();
            #pragma unroll
            for (int ks = 0; ks < 4; ++ks) {
                const int cb = ks * 2 + khalf;               // wanted colblock
                short8 af[2], bfr[2];
                #pragma unroll
                for (int mi = 0; mi < 2; ++mi) {
                    const int swz = (cb ^ l7 ^ ((wr * 8 + mi * 4 + (l31 >> 3)) & 7)) * 8;
                    af[mi] = *(const short8*)(smA + (wr * 64 + mi * 32 + l31) * 64 + swz);
                }
                #pragma unroll
                for (int ni = 0; ni < 2; ++ni) {
                    const int swz = (cb ^ l7 ^ ((wc * 8 + ni * 4 + (l31 >> 3)) & 7)) * 8;
                    bfr[ni] = *(const short8*)(smB + (wc * 64 + ni * 32 + l31) * 64 + swz);
                }
                #pragma unroll
                for (int mi = 0; mi < 2; ++mi)
                    #pragma unroll
                    for (int ni = 0; ni < 2; ++ni)
                        acc[mi][ni] = __builtin_amdgcn_mfma_f32_32x32x16_bf16(
                            af[mi], bfr[ni], acc[mi][ni], 0, 0, 0);
            }
            __syncthreads();
        }

        if (tower == 0) {
            // epilogue u: bias + LeakyReLU, pack to bf16 (halve live regs)
            #pragma unroll
            for (int ni = 0; ni < 2; ++ni) {
                const float bias = b_u[ncol0 + wc * 64 + ni * 32 + l31];
                #pragma unroll
                for (int mi = 0; mi < 2; ++mi) {
                    #pragma unroll
                    for (int p = 0; p < 8; ++p) {
                        float h0 = acc[mi][ni][p * 2] + bias;
                        float h1 = acc[mi][ni][p * 2 + 1] + bias;
                        h0 = h0 >= 0.f ? h0 : SLOPE * h0;
                        h1 = h1 >= 0.f ? h1 : SLOPE * h1;
                        hu_pk[mi][ni][p] = (unsigned)f2bf(h0) | ((unsigned)f2bf(h1) << 16);
                    }
                }
            }
        }
    }

    // final epilogue: hv = leaky(acc_v + b_v); prod = hu*hv; reduce over cols
    // (lanes 0..31 hold all 32 cols of a row); atomicAdd per row.
    // reg-chunked (4 at a time) to cap live registers.
    #pragma unroll
    for (int mi = 0; mi < 2; ++mi) {
        #pragma unroll
        for (int rg = 0; rg < 4; ++rg) {
            float rsum[4] = {0.f, 0.f, 0.f, 0.f};
            #pragma unroll
            for (int ni = 0; ni < 2; ++ni) {
                const float bias = b_v[ncol0 + wc * 64 + ni * 32 + l31];
                #pragma unroll
                for (int r = 0; r < 4; ++r) {
                    const int reg = rg * 4 + r;
                    float hv = acc[mi][ni][reg] + bias;
                    hv = hv >= 0.f ? hv : SLOPE * hv;
                    const unsigned pk = hu_pk[mi][ni][reg >> 1];
                    const unsigned bits = (reg & 1) ? (pk & 0xFFFF0000u) : (pk << 16);
                    rsum[r] += __uint_as_float(bits) * hv;
                }
            }
            #pragma unroll
            for (int r = 0; r < 4; ++r) {
                const int reg = rg * 4 + r;
                float vsum = rsum[r];
                vsum += __shfl_xor(vsum, 1);
                vsum += __shfl_xor(vsum, 2);
                vsum += __shfl_xor(vsum, 4);
                vsum += __shfl_xor(vsum, 8);
                vsum += __shfl_xor(vsum, 16);
                if (l31 == 0) {
                    const int row = (int)arow0 + wr * 64 + mi * 32
                                  + (reg & 3) + 8 * (reg >> 2) + 4 * khalf;
                    atomicAdd(out + row, vsum);
                }
            }
        }
    }
}

extern "C" void kernel_launch(void* const* d_in, const int* in_sizes, int n_in,
                              void* d_out, int out_size, void* d_ws, size_t ws_size,
                              hipStream_t stream)
{
    const float* u     = (const float*)d_in[0];
    const float* v     = (const float*)d_in[1];
    const float* lnu_w = (const float*)d_in[2];
    const float* lnu_b = (const float*)d_in[3];
    const float* lnv_w = (const float*)d_in[4];
    const float* lnv_b = (const float*)d_in[5];
    const float* W_u   = (const float*)d_in[6];
    const float* b_u   = (const float*)d_in[7];
    const float* W_v   = (const float*)d_in[8];
    const float* b_v   = (const float*)d_in[9];
    float* out = (float*)d_out;

    char* ws = (char*)d_ws;
    u16* Au  = (u16*)(ws);                                              // 33.5 MB
    u16* Av  = (u16*)(ws + (size_t)NROWS * DIM * 2);                    // 33.5 MB
    u16* WtU = (u16*)(ws + (size_t)NROWS * DIM * 4);                    //  8.4 MB
    u16* WtV = (u16*)(ws + (size_t)NROWS * DIM * 4 + (size_t)DIM * DIM * 2); // 8.4 MB

    hipMemsetAsync(d_out, 0, (size_t)out_size * sizeof(float), stream);
    prep_kernel<<<LN_BLOCKS + WT_BLOCKS, 256, 0, stream>>>(
        u, v, lnu_w, lnu_b, lnv_w, lnv_b, W_u, W_v, Au, Av, WtU, WtV);
    fused_gemm_dot<<<dim3(NROWS / 128, DIM / 128), 256, 0, stream>>>(Au, Av, WtU, WtV, b_u, b_v, out);
}

// Round 6
// 344.449 us; speedup vs baseline: 1.2019x; 1.2019x over previous
//
#include <hip/hip_runtime.h>

typedef unsigned short u16;
typedef __attribute__((ext_vector_type(8))) short short8;
typedef __attribute__((ext_vector_type(16))) float f32x16;

#define DIM 2048
#define NROWS 8192
#define SLOPE 0.001f
#define LN_EPS 1e-5f

#define LN_BLOCKS 4096              // 16384 rows, 4 rows (waves) per block
#define WT_BLOCKS 2048              // 2 towers * (2048/64)^2 tiles

__device__ __forceinline__ u16 f2bf(float f) {
    unsigned int u = __float_as_uint(f);
    u += 0x7FFFu + ((u >> 16) & 1u);   // round-to-nearest-even
    return (u16)(u >> 16);
}

__device__ __forceinline__ void gload_lds16(const void* g, void* l) {
    __builtin_amdgcn_global_load_lds(
        (const __attribute__((address_space(1))) void*)g,
        (__attribute__((address_space(3))) void*)l, 16, 0, 0);
}

// ---------------- Kernel 1: fused prep ----------------
// blocks [0, LN_BLOCKS): LayerNorm + bf16 cast, one wave per row.
// blocks [LN_BLOCKS, LN_BLOCKS+WT_BLOCKS): W[k][n] -> Wt[n][k] bf16, 64x64 tile.
__global__ __launch_bounds__(256) void prep_kernel(
    const float* __restrict__ u, const float* __restrict__ v,
    const float* __restrict__ lnu_w, const float* __restrict__ lnu_b,
    const float* __restrict__ lnv_w, const float* __restrict__ lnv_b,
    const float* __restrict__ Wu, const float* __restrict__ Wv,
    u16* __restrict__ Au, u16* __restrict__ Av,
    u16* __restrict__ WtU, u16* __restrict__ WtV)
{
    __shared__ u16 tile[64][66];   // WT staging; stride 66 u16 -> 2-way banks (free)

    if (blockIdx.x < LN_BLOCKS) {
        // ---- LayerNorm path: one wave per row, pure shfl reduce ----
        const int wave = threadIdx.x >> 6;
        const int lane = threadIdx.x & 63;
        const int r = blockIdx.x * 4 + wave;          // 0 .. 2*NROWS-1
        const bool isv = r >= NROWS;
        const int row = isv ? (r - NROWS) : r;
        const float* __restrict__ src = (isv ? v : u) + (size_t)row * DIM;
        const float* __restrict__ gw = isv ? lnv_w : lnu_w;
        const float* __restrict__ gb = isv ? lnv_b : lnu_b;
        u16* __restrict__ dst = (isv ? Av : Au) + (size_t)row * DIM;

        float4 x[8];
        #pragma unroll
        for (int i = 0; i < 8; ++i)
            x[i] = *(const float4*)(src + i * 256 + lane * 4);

        float s = 0.f, s2 = 0.f;
        #pragma unroll
        for (int i = 0; i < 8; ++i) {
            s  += (x[i].x + x[i].y) + (x[i].z + x[i].w);
            s2 += x[i].x*x[i].x + x[i].y*x[i].y + x[i].z*x[i].z + x[i].w*x[i].w;
        }
        #pragma unroll
        for (int m = 1; m < 64; m <<= 1) {
            s  += __shfl_xor(s, m);
            s2 += __shfl_xor(s2, m);
        }
        const float mu = s * (1.0f / DIM);
        const float rstd = rsqrtf(s2 * (1.0f / DIM) - mu * mu + LN_EPS);

        #pragma unroll
        for (int i = 0; i < 8; ++i) {
            const float4 w4 = *(const float4*)(gw + i * 256 + lane * 4);
            const float4 b4 = *(const float4*)(gb + i * 256 + lane * 4);
            union { u16 us[4]; uint2 v2; } pk;
            pk.us[0] = f2bf((x[i].x - mu) * rstd * w4.x + b4.x);
            pk.us[1] = f2bf((x[i].y - mu) * rstd * w4.y + b4.y);
            pk.us[2] = f2bf((x[i].z - mu) * rstd * w4.z + b4.z);
            pk.us[3] = f2bf((x[i].w - mu) * rstd * w4.w + b4.w);
            *(uint2*)(dst + i * 256 + lane * 4) = pk.v2;
        }
    } else {
        // ---- transpose+cast path: 64x64 tile ----
        const int b = blockIdx.x - LN_BLOCKS;          // 0..2047
        const int tower = b >> 10;                     // 1024 tiles per tower
        const int t6 = b & 1023;
        const int n0 = (t6 & 31) * 64;
        const int k0 = (t6 >> 5) * 64;
        const float* __restrict__ src = tower ? Wv : Wu;
        u16* __restrict__ dst = tower ? WtV : WtU;
        const int c  = threadIdx.x & 15;               // col group (4 floats)
        const int rq = threadIdx.x >> 4;               // 0..15

        #pragma unroll
        for (int i = 0; i < 4; ++i) {
            const int k = rq + 16 * i;
            const float4 w = *(const float4*)(src + (size_t)(k0 + k) * DIM + n0 + c * 4);
            union { u16 us[4]; uint2 v2; } pk;
            pk.us[0] = f2bf(w.x); pk.us[1] = f2bf(w.y);
            pk.us[2] = f2bf(w.z); pk.us[3] = f2bf(w.w);
            *(uint2*)&tile[k][c * 4] = pk.v2;
        }
        __syncthreads();
        #pragma unroll
        for (int i = 0; i < 4; ++i) {
            const int n = rq + 16 * i;
            union { u16 us[4]; uint2 v2; } pk;
            #pragma unroll
            for (int j = 0; j < 4; ++j) pk.us[j] = tile[c * 4 + j][n];
            *(uint2*)(dst + (size_t)(n0 + n) * DIM + k0 + c * 4) = pk.v2;
        }
    }
}

// ---------------- Kernel 2: fused dual GEMM + bias + LeakyReLU + row dot ----------------
// 128x128 C tile per block, 256 threads = 4 waves, each wave a 64x64 quadrant
// as a 2x2 grid of 32x32x16 bf16 MFMA. BK=64, global_load_lds width-16 staging.
// LDS swizzle: slot s of row r holds global colblock s ^ (r&7) ^ ((r>>3)&7)
// -> 0 bank conflicts (verified R5). NOTE: no min-waves launch_bounds arg --
// R5's (256,3) forced VGPR 116->84 and spilled (WRITE_SIZE 4->45 MB, +64 us).
// C/D layout (m74/m101): col = lane&31, row = (reg&3) + 8*(reg>>2) + 4*(lane>>5).
__global__ __launch_bounds__(256) void fused_gemm_dot(
    const u16* __restrict__ Au, const u16* __restrict__ Av,
    const u16* __restrict__ WtU, const u16* __restrict__ WtV,
    const float* __restrict__ b_u, const float* __restrict__ b_v,
    float* __restrict__ out)
{
    __shared__ u16 smA[128 * 64];
    __shared__ u16 smB[128 * 64];

    const int tid  = threadIdx.x;
    const int wave = tid >> 6;
    const int lane = tid & 63;
    const int l31  = lane & 31;   // fragment row (A) / col (B,C)
    const int khalf = lane >> 5;  // which 8-wide k-half the lane holds
    const int wr = wave >> 1;     // wave row half (0..1)
    const int wc = wave & 1;      // wave col half (0..1)

    const int bm = blockIdx.x;    // 0..63
    const int bn = blockIdx.y;    // 0..15
    const size_t arow0 = (size_t)bm * 128;
    const size_t ncol0 = (size_t)bn * 128;

    // staging: lane covers row (rg + lane>>3); to realize the slot mapping,
    // lane fetches global colblock (lane&7) ^ ((lane>>3)&7) ^ ((rg>>3)&7).
    const int srow = lane >> 3;
    const int sblk0 = (lane & 7) ^ (srow & 7);   // ^ per-instr (rg>>3)&7 below

    const int l7 = l31 & 7;

    f32x16 acc[2][2];
    unsigned int hu_pk[2][2][8];  // tower-u activations, packed bf16 pairs

    #pragma unroll
    for (int tower = 0; tower < 2; ++tower) {
        const u16* __restrict__ Abase = (tower ? Av : Au) + arow0 * DIM;
        const u16* __restrict__ Bbase = (tower ? WtV : WtU) + ncol0 * DIM;

        #pragma unroll
        for (int mi = 0; mi < 2; ++mi)
            #pragma unroll
            for (int ni = 0; ni < 2; ++ni)
                #pragma unroll
                for (int r = 0; r < 16; ++r)
                    acc[mi][ni][r] = 0.f;

        for (int k0 = 0; k0 < DIM; k0 += 64) {
            #pragma unroll
            for (int i = 0; i < 4; ++i) {
                const int rg = i * 32 + wave * 8;            // wave-uniform row group
                const int scol = (sblk0 ^ ((rg >> 3) & 7)) * 8;
                gload_lds16(Abase + (size_t)(rg + srow) * DIM + k0 + scol, smA + rg * 64);
                gload_lds16(Bbase + (size_t)(rg + srow) * DIM + k0 + scol, smB + rg * 64);
            }
            __syncthreads();
            #pragma unroll
            for (int ks = 0; ks < 4; ++ks) {
                const int cb = ks * 2 + khalf;               // wanted colblock
                short8 af[2], bfr[2];
                #pragma unroll
                for (int mi = 0; mi < 2; ++mi) {
                    const int swz = (cb ^ l7 ^ ((wr * 8 + mi * 4 + (l31 >> 3)) & 7)) * 8;
                    af[mi] = *(const short8*)(smA + (wr * 64 + mi * 32 + l31) * 64 + swz);
                }
                #pragma unroll
                for (int ni = 0; ni < 2; ++ni) {
                    const int swz = (cb ^ l7 ^ ((wc * 8 + ni * 4 + (l31 >> 3)) & 7)) * 8;
                    bfr[ni] = *(const short8*)(smB + (wc * 64 + ni * 32 + l31) * 64 + swz);
                }
                #pragma unroll
                for (int mi = 0; mi < 2; ++mi)
                    #pragma unroll
                    for (int ni = 0; ni < 2; ++ni)
                        acc[mi][ni] = __builtin_amdgcn_mfma_f32_32x32x16_bf16(
                            af[mi], bfr[ni], acc[mi][ni], 0, 0, 0);
            }
            __syncthreads();
        }

        if (tower == 0) {
            // epilogue u: bias + LeakyReLU, pack to bf16 (halve live regs)
            #pragma unroll
            for (int ni = 0; ni < 2; ++ni) {
                const float bias = b_u[ncol0 + wc * 64 + ni * 32 + l31];
                #pragma unroll
                for (int mi = 0; mi < 2; ++mi) {
                    #pragma unroll
                    for (int p = 0; p < 8; ++p) {
                        float h0 = acc[mi][ni][p * 2] + bias;
                        float h1 = acc[mi][ni][p * 2 + 1] + bias;
                        h0 = h0 >= 0.f ? h0 : SLOPE * h0;
                        h1 = h1 >= 0.f ? h1 : SLOPE * h1;
                        hu_pk[mi][ni][p] = (unsigned)f2bf(h0) | ((unsigned)f2bf(h1) << 16);
                    }
                }
            }
        }
    }

    // final epilogue: hv = leaky(acc_v + b_v); prod = hu*hv; reduce over cols
    // (lanes 0..31 hold all 32 cols of a row); atomicAdd per row.
    // reg-chunked (4 at a time) to cap live registers.
    #pragma unroll
    for (int mi = 0; mi < 2; ++mi) {
        #pragma unroll
        for (int rg = 0; rg < 4; ++rg) {
            float rsum[4] = {0.f, 0.f, 0.f, 0.f};
            #pragma unroll
            for (int ni = 0; ni < 2; ++ni) {
                const float bias = b_v[ncol0 + wc * 64 + ni * 32 + l31];
                #pragma unroll
                for (int r = 0; r < 4; ++r) {
                    const int reg = rg * 4 + r;
                    float hv = acc[mi][ni][reg] + bias;
                    hv = hv >= 0.f ? hv : SLOPE * hv;
                    const unsigned pk = hu_pk[mi][ni][reg >> 1];
                    const unsigned bits = (reg & 1) ? (pk & 0xFFFF0000u) : (pk << 16);
                    rsum[r] += __uint_as_float(bits) * hv;
                }
            }
            #pragma unroll
            for (int r = 0; r < 4; ++r) {
                const int reg = rg * 4 + r;
                float vsum = rsum[r];
                vsum += __shfl_xor(vsum, 1);
                vsum += __shfl_xor(vsum, 2);
                vsum += __shfl_xor(vsum, 4);
                vsum += __shfl_xor(vsum, 8);
                vsum += __shfl_xor(vsum, 16);
                if (l31 == 0) {
                    const int row = (int)arow0 + wr * 64 + mi * 32
                                  + (reg & 3) + 8 * (reg >> 2) + 4 * khalf;
                    atomicAdd(out + row, vsum);
                }
            }
        }
    }
}

extern "C" void kernel_launch(void* const* d_in, const int* in_sizes, int n_in,
                              void* d_out, int out_size, void* d_ws, size_t ws_size,
                              hipStream_t stream)
{
    const float* u     = (const float*)d_in[0];
    const float* v     = (const float*)d_in[1];
    const float* lnu_w = (const float*)d_in[2];
    const float* lnu_b = (const float*)d_in[3];
    const float* lnv_w = (const float*)d_in[4];
    const float* lnv_b = (const float*)d_in[5];
    const float* W_u   = (const float*)d_in[6];
    const float* b_u   = (const float*)d_in[7];
    const float* W_v   = (const float*)d_in[8];
    const float* b_v   = (const float*)d_in[9];
    float* out = (float*)d_out;

    char* ws = (char*)d_ws;
    u16* Au  = (u16*)(ws);                                              // 33.5 MB
    u16* Av  = (u16*)(ws + (size_t)NROWS * DIM * 2);                    // 33.5 MB
    u16* WtU = (u16*)(ws + (size_t)NROWS * DIM * 4);                    //  8.4 MB
    u16* WtV = (u16*)(ws + (size_t)NROWS * DIM * 4 + (size_t)DIM * DIM * 2); // 8.4 MB

    hipMemsetAsync(d_out, 0, (size_t)out_size * sizeof(float), stream);
    prep_kernel<<<LN_BLOCKS + WT_BLOCKS, 256, 0, stream>>>(
        u, v, lnu_w, lnu_b, lnv_w, lnv_b, W_u, W_v, Au, Av, WtU, WtV);
    fused_gemm_dot<<<dim3(NROWS / 128, DIM / 128), 256, 0, stream>>>(Au, Av, WtU, WtV, b_u, b_v, out);
}